// Round 1
// baseline (353.108 us; speedup 1.0000x reference)
//
#include <hip/hip_runtime.h>
#include <math.h>

#define HC 4
#define HIDDEN 4096
#define DIM (HC * HIDDEN)          // 16384 floats per row
#define MIXN ((2 + HC) * HC)       // 24
#define RPB 4                      // rows per block
#define THREADS 256
#define NROWS (2 * 4096)           // B*S = 8192
#define HC_EPS 1e-5f
#define NORM_EPS 1e-6f

#define PRE_OFF 0
#define POST_OFF (NROWS * HC)            // 32768
#define COMB_OFF (2 * NROWS * HC)        // 65536

__global__ __launch_bounds__(THREADS) void hyperconn_kernel(
    const float* __restrict__ hs,    // [NROWS][DIM]
    const float* __restrict__ fn,    // [MIXN][DIM]
    const float* __restrict__ base,  // [MIXN]
    const float* __restrict__ scale, // [3]
    float* __restrict__ out)
{
    const int tid = threadIdx.x;
    const int row0 = blockIdx.x * RPB;

    float acc[RPB][MIXN];
    float ssq[RPB];
    #pragma unroll
    for (int r = 0; r < RPB; ++r) {
        ssq[r] = 0.0f;
        #pragma unroll
        for (int m = 0; m < MIXN; ++m) acc[r][m] = 0.0f;
    }

    const float4* __restrict__ fn4 = reinterpret_cast<const float4*>(fn);
    const float4* __restrict__ hs4 =
        reinterpret_cast<const float4*>(hs) + (size_t)row0 * (DIM / 4);

    // main loop: d partitioned across threads, float4 granularity, coalesced
    #pragma unroll 1
    for (int k = 0; k < DIM / 4 / THREADS; ++k) {   // 16 iterations
        const int d4 = k * THREADS + tid;

        float4 x[RPB];
        #pragma unroll
        for (int r = 0; r < RPB; ++r) x[r] = hs4[(size_t)r * (DIM / 4) + d4];

        #pragma unroll
        for (int r = 0; r < RPB; ++r) {
            ssq[r] = fmaf(x[r].x, x[r].x, ssq[r]);
            ssq[r] = fmaf(x[r].y, x[r].y, ssq[r]);
            ssq[r] = fmaf(x[r].z, x[r].z, ssq[r]);
            ssq[r] = fmaf(x[r].w, x[r].w, ssq[r]);
        }

        #pragma unroll
        for (int m = 0; m < MIXN; ++m) {
            const float4 f = fn4[m * (DIM / 4) + d4];
            #pragma unroll
            for (int r = 0; r < RPB; ++r) {
                acc[r][m] = fmaf(x[r].x, f.x, acc[r][m]);
                acc[r][m] = fmaf(x[r].y, f.y, acc[r][m]);
                acc[r][m] = fmaf(x[r].z, f.z, acc[r][m]);
                acc[r][m] = fmaf(x[r].w, f.w, acc[r][m]);
            }
        }
    }

    // wave-level butterfly reduce (64 lanes), all 100 values
    #pragma unroll
    for (int r = 0; r < RPB; ++r) {
        #pragma unroll
        for (int m = 0; m < MIXN; ++m) {
            float v = acc[r][m];
            #pragma unroll
            for (int off = 32; off >= 1; off >>= 1) v += __shfl_xor(v, off, 64);
            acc[r][m] = v;
        }
        float v = ssq[r];
        #pragma unroll
        for (int off = 32; off >= 1; off >>= 1) v += __shfl_xor(v, off, 64);
        ssq[r] = v;
    }

    // cross-wave combine via LDS
    __shared__ float s_red[THREADS / 64][RPB * 25];
    __shared__ float s_fin[RPB * 25];
    const int wave = tid >> 6;
    const int lane = tid & 63;
    if (lane == 0) {
        #pragma unroll
        for (int r = 0; r < RPB; ++r) {
            #pragma unroll
            for (int m = 0; m < MIXN; ++m) s_red[wave][r * 25 + m] = acc[r][m];
            s_red[wave][r * 25 + 24] = ssq[r];
        }
    }
    __syncthreads();
    if (tid < RPB * 25) {
        s_fin[tid] = s_red[0][tid] + s_red[1][tid] + s_red[2][tid] + s_red[3][tid];
    }
    __syncthreads();

    // epilogue: one thread per row
    if (tid < RPB) {
        const int r = tid;
        const int row = row0 + r;
        const float* v = &s_fin[r * 25];
        const float rs = 1.0f / sqrtf(v[24] * (1.0f / (float)DIM) + NORM_EPS);
        const float s0 = scale[0], s1 = scale[1], s2 = scale[2];

        // pre = sigmoid(mix[:4]*s0 + base[:4]) + eps
        #pragma unroll
        for (int i = 0; i < HC; ++i) {
            const float z = v[i] * rs * s0 + base[i];
            out[PRE_OFF + row * HC + i] = 1.0f / (1.0f + expf(-z)) + HC_EPS;
        }
        // post = 2*sigmoid(mix[4:8]*s1 + base[4:8])
        #pragma unroll
        for (int i = 0; i < HC; ++i) {
            const float z = v[HC + i] * rs * s1 + base[HC + i];
            out[POST_OFF + row * HC + i] = 2.0f / (1.0f + expf(-z));
        }

        // comb: softmax over j, +eps, then Sinkhorn normalizations
        float c[HC][HC];
        #pragma unroll
        for (int i = 0; i < HC; ++i) {
            float l[HC];
            #pragma unroll
            for (int j = 0; j < HC; ++j)
                l[j] = v[2 * HC + i * HC + j] * rs * s2 + base[2 * HC + i * HC + j];
            const float mx = fmaxf(fmaxf(l[0], l[1]), fmaxf(l[2], l[3]));
            float e[HC];
            float sum = 0.0f;
            #pragma unroll
            for (int j = 0; j < HC; ++j) { e[j] = expf(l[j] - mx); sum += e[j]; }
            const float inv = 1.0f / sum;
            #pragma unroll
            for (int j = 0; j < HC; ++j) c[i][j] = e[j] * inv + HC_EPS;
        }
        // first column normalize (axis=-2)
        #pragma unroll
        for (int j = 0; j < HC; ++j) {
            const float cs = c[0][j] + c[1][j] + c[2][j] + c[3][j] + HC_EPS;
            const float inv = 1.0f / cs;
            c[0][j] *= inv; c[1][j] *= inv; c[2][j] *= inv; c[3][j] *= inv;
        }
        // 4 more Sinkhorn iterations: row norm then col norm
        #pragma unroll
        for (int it = 0; it < 4; ++it) {
            #pragma unroll
            for (int i = 0; i < HC; ++i) {
                const float rsum = c[i][0] + c[i][1] + c[i][2] + c[i][3] + HC_EPS;
                const float inv = 1.0f / rsum;
                c[i][0] *= inv; c[i][1] *= inv; c[i][2] *= inv; c[i][3] *= inv;
            }
            #pragma unroll
            for (int j = 0; j < HC; ++j) {
                const float cs = c[0][j] + c[1][j] + c[2][j] + c[3][j] + HC_EPS;
                const float inv = 1.0f / cs;
                c[0][j] *= inv; c[1][j] *= inv; c[2][j] *= inv; c[3][j] *= inv;
            }
        }
        #pragma unroll
        for (int i = 0; i < HC; ++i)
            #pragma unroll
            for (int j = 0; j < HC; ++j)
                out[COMB_OFF + row * (HC * HC) + i * HC + j] = c[i][j];
    }
}

extern "C" void kernel_launch(void* const* d_in, const int* in_sizes, int n_in,
                              void* d_out, int out_size, void* d_ws, size_t ws_size,
                              hipStream_t stream) {
    const float* hs    = (const float*)d_in[0];
    const float* fn    = (const float*)d_in[1];
    const float* base  = (const float*)d_in[2];
    const float* scale = (const float*)d_in[3];
    float* out = (float*)d_out;

    const int grid = NROWS / RPB;  // 2048 blocks
    hyperconn_kernel<<<grid, THREADS, 0, stream>>>(hs, fn, base, scale, out);
}

// Round 3
// 334.594 us; speedup vs baseline: 1.0553x; 1.0553x over previous
//
#include <hip/hip_runtime.h>
#include <math.h>

#define HC 4
#define HIDDEN 4096
#define DIM (HC * HIDDEN)          // 16384 floats per row
#define MIXN ((2 + HC) * HC)       // 24
#define RPB 4                      // rows per block
#define THREADS 256
#define NROWS (2 * 4096)           // B*S = 8192
#define HC_EPS 1e-5f
#define NORM_EPS 1e-6f

#define PRE_OFF 0
#define POST_OFF (NROWS * HC)            // 32768
#define COMB_OFF (2 * NROWS * HC)        // 65536

typedef float f32x4 __attribute__((ext_vector_type(4)));

__global__ __launch_bounds__(THREADS) void hyperconn_kernel(
    const float* __restrict__ hs,    // [NROWS][DIM]  (streamed once -> nontemporal)
    const float* __restrict__ fn,    // [MIXN][DIM]   (reused by all blocks -> keep cached)
    const float* __restrict__ base,  // [MIXN]
    const float* __restrict__ scale, // [3]
    float* __restrict__ out)
{
    const int tid = threadIdx.x;
    const int row0 = blockIdx.x * RPB;

    float acc[RPB][MIXN];
    float ssq[RPB];
    #pragma unroll
    for (int r = 0; r < RPB; ++r) {
        ssq[r] = 0.0f;
        #pragma unroll
        for (int m = 0; m < MIXN; ++m) acc[r][m] = 0.0f;
    }

    const f32x4* __restrict__ fn4 = reinterpret_cast<const f32x4*>(fn);
    const f32x4* __restrict__ hs4 =
        reinterpret_cast<const f32x4*>(hs) + (size_t)row0 * (DIM / 4);

    constexpr int KITER = DIM / 4 / THREADS;  // 16

    // software prefetch of the HBM stream (hs): load iter k+1 while FMAing iter k.
    // nontemporal -> evict-first in L2 so fn stays L2-resident.
    f32x4 xn[RPB];
    #pragma unroll
    for (int r = 0; r < RPB; ++r)
        xn[r] = __builtin_nontemporal_load(&hs4[(size_t)r * (DIM / 4) + tid]);

    #pragma unroll 1
    for (int k = 0; k < KITER; ++k) {
        const int d4 = k * THREADS + tid;

        f32x4 x[RPB];
        #pragma unroll
        for (int r = 0; r < RPB; ++r) x[r] = xn[r];

        // prefetch next iteration's hs (clamped on last iter to stay in-bounds)
        const int d4n = (k + 1 < KITER) ? (k + 1) * THREADS + tid : tid;
        #pragma unroll
        for (int r = 0; r < RPB; ++r)
            xn[r] = __builtin_nontemporal_load(&hs4[(size_t)r * (DIM / 4) + d4n]);

        #pragma unroll
        for (int r = 0; r < RPB; ++r) {
            ssq[r] = fmaf(x[r].x, x[r].x, ssq[r]);
            ssq[r] = fmaf(x[r].y, x[r].y, ssq[r]);
            ssq[r] = fmaf(x[r].z, x[r].z, ssq[r]);
            ssq[r] = fmaf(x[r].w, x[r].w, ssq[r]);
        }

        #pragma unroll
        for (int m = 0; m < MIXN; ++m) {
            const f32x4 f = fn4[m * (DIM / 4) + d4];
            #pragma unroll
            for (int r = 0; r < RPB; ++r) {
                acc[r][m] = fmaf(x[r].x, f.x, acc[r][m]);
                acc[r][m] = fmaf(x[r].y, f.y, acc[r][m]);
                acc[r][m] = fmaf(x[r].z, f.z, acc[r][m]);
                acc[r][m] = fmaf(x[r].w, f.w, acc[r][m]);
            }
        }
    }

    // wave-level butterfly reduce (64 lanes), all 100 values
    #pragma unroll
    for (int r = 0; r < RPB; ++r) {
        #pragma unroll
        for (int m = 0; m < MIXN; ++m) {
            float v = acc[r][m];
            #pragma unroll
            for (int off = 32; off >= 1; off >>= 1) v += __shfl_xor(v, off, 64);
            acc[r][m] = v;
        }
        float v = ssq[r];
        #pragma unroll
        for (int off = 32; off >= 1; off >>= 1) v += __shfl_xor(v, off, 64);
        ssq[r] = v;
    }

    // cross-wave combine via LDS
    __shared__ float s_red[THREADS / 64][RPB * 25];
    __shared__ float s_fin[RPB * 25];
    const int wave = tid >> 6;
    const int lane = tid & 63;
    if (lane == 0) {
        #pragma unroll
        for (int r = 0; r < RPB; ++r) {
            #pragma unroll
            for (int m = 0; m < MIXN; ++m) s_red[wave][r * 25 + m] = acc[r][m];
            s_red[wave][r * 25 + 24] = ssq[r];
        }
    }
    __syncthreads();
    if (tid < RPB * 25) {
        s_fin[tid] = s_red[0][tid] + s_red[1][tid] + s_red[2][tid] + s_red[3][tid];
    }
    __syncthreads();

    // epilogue: one thread per row
    if (tid < RPB) {
        const int r = tid;
        const int row = row0 + r;
        const float* v = &s_fin[r * 25];
        const float rs = 1.0f / sqrtf(v[24] * (1.0f / (float)DIM) + NORM_EPS);
        const float s0 = scale[0], s1 = scale[1], s2 = scale[2];

        // pre = sigmoid(mix[:4]*s0 + base[:4]) + eps
        #pragma unroll
        for (int i = 0; i < HC; ++i) {
            const float z = v[i] * rs * s0 + base[i];
            out[PRE_OFF + row * HC + i] = 1.0f / (1.0f + expf(-z)) + HC_EPS;
        }
        // post = 2*sigmoid(mix[4:8]*s1 + base[4:8])
        #pragma unroll
        for (int i = 0; i < HC; ++i) {
            const float z = v[HC + i] * rs * s1 + base[HC + i];
            out[POST_OFF + row * HC + i] = 2.0f / (1.0f + expf(-z));
        }

        // comb: softmax over j, +eps, then Sinkhorn normalizations
        float c[HC][HC];
        #pragma unroll
        for (int i = 0; i < HC; ++i) {
            float l[HC];
            #pragma unroll
            for (int j = 0; j < HC; ++j)
                l[j] = v[2 * HC + i * HC + j] * rs * s2 + base[2 * HC + i * HC + j];
            const float mx = fmaxf(fmaxf(l[0], l[1]), fmaxf(l[2], l[3]));
            float e[HC];
            float sum = 0.0f;
            #pragma unroll
            for (int j = 0; j < HC; ++j) { e[j] = expf(l[j] - mx); sum += e[j]; }
            const float inv = 1.0f / sum;
            #pragma unroll
            for (int j = 0; j < HC; ++j) c[i][j] = e[j] * inv + HC_EPS;
        }
        // first column normalize (axis=-2)
        #pragma unroll
        for (int j = 0; j < HC; ++j) {
            const float cs = c[0][j] + c[1][j] + c[2][j] + c[3][j] + HC_EPS;
            const float inv = 1.0f / cs;
            c[0][j] *= inv; c[1][j] *= inv; c[2][j] *= inv; c[3][j] *= inv;
        }
        // 4 more Sinkhorn iterations: row norm then col norm
        #pragma unroll
        for (int it = 0; it < 4; ++it) {
            #pragma unroll
            for (int i = 0; i < HC; ++i) {
                const float rsum = c[i][0] + c[i][1] + c[i][2] + c[i][3] + HC_EPS;
                const float inv = 1.0f / rsum;
                c[i][0] *= inv; c[i][1] *= inv; c[i][2] *= inv; c[i][3] *= inv;
            }
            #pragma unroll
            for (int j = 0; j < HC; ++j) {
                const float cs = c[0][j] + c[1][j] + c[2][j] + c[3][j] + HC_EPS;
                const float inv = 1.0f / cs;
                c[0][j] *= inv; c[1][j] *= inv; c[2][j] *= inv; c[3][j] *= inv;
            }
        }
        #pragma unroll
        for (int i = 0; i < HC; ++i)
            #pragma unroll
            for (int j = 0; j < HC; ++j)
                out[COMB_OFF + row * (HC * HC) + i * HC + j] = c[i][j];
    }
}

extern "C" void kernel_launch(void* const* d_in, const int* in_sizes, int n_in,
                              void* d_out, int out_size, void* d_ws, size_t ws_size,
                              hipStream_t stream) {
    const float* hs    = (const float*)d_in[0];
    const float* fn    = (const float*)d_in[1];
    const float* base  = (const float*)d_in[2];
    const float* scale = (const float*)d_in[3];
    float* out = (float*)d_out;

    const int grid = NROWS / RPB;  // 2048 blocks
    hyperconn_kernel<<<grid, THREADS, 0, stream>>>(hs, fn, base, scale, out);
}